// Round 1
// baseline (608.168 us; speedup 1.0000x reference)
//
#include <hip/hip_runtime.h>
#include <stdint.h>
#include <stddef.h>

#define D_MODEL 1024
#define SEQ     4096
#define BATCH   4
#define MTOT    (BATCH*SEQ)     // 16384
#define NWIN    63
#define PSTR    136             // P row stride in bf16 elements (128 + 8 pad, keeps 16B align)

typedef __bf16 bf16;
typedef __bf16 bf16x8 __attribute__((ext_vector_type(8)));
typedef __bf16 bf16x4 __attribute__((ext_vector_type(4)));
typedef float  floatx4 __attribute__((ext_vector_type(4)));

// async global->LDS, 16B per lane. LDS dest is wave-uniform base + lane*16.
__device__ __forceinline__ void async_ld16(const void* g, void* l) {
  __builtin_amdgcn_global_load_lds(
      (const __attribute__((address_space(1))) unsigned int*)g,
      (__attribute__((address_space(3))) unsigned int*)l,
      16, 0, 0);
}

// ---------------- elementwise converts ----------------

__global__ __launch_bounds__(256)
void cvt_x_kernel(const float* __restrict__ x, bf16* __restrict__ xb)
{
  const int i = blockIdx.x * 256 + threadIdx.x;   // exactly 4M threads (16M elems /4)
  const float4 v = ((const float4*)x)[i];
  bf16x4 o = { (bf16)v.x, (bf16)v.y, (bf16)v.z, (bf16)v.w };
  ((bf16x4*)xb)[i] = o;
}

// W (fp32, [K][N]) -> Wt (bf16, [N][K]) for 4 weight matrices (blockIdx.z selects)
__global__ __launch_bounds__(256)
void cvt_wt_kernel(const float* __restrict__ W0, const float* __restrict__ W1,
                   const float* __restrict__ W2, const float* __restrict__ W3,
                   bf16* __restrict__ wt)
{
  __shared__ float tile[32][33];
  const float* Wsel = (blockIdx.z == 0) ? W0 : (blockIdx.z == 1) ? W1
                    : (blockIdx.z == 2) ? W2 : W3;
  bf16* Wt = wt + (size_t)blockIdx.z * D_MODEL * D_MODEL;
  const int tx = threadIdx.x & 31, ty = threadIdx.x >> 5;  // 32 x 8
  const int tn = blockIdx.x * 32, tk = blockIdx.y * 32;
#pragma unroll
  for (int j = 0; j < 32; j += 8)
    tile[ty + j][tx] = Wsel[(size_t)(tk + ty + j) * D_MODEL + (tn + tx)];
  __syncthreads();
#pragma unroll
  for (int j = 0; j < 32; j += 8)
    Wt[(size_t)(tn + ty + j) * D_MODEL + (tk + tx)] = (bf16)tile[tx][ty + j];
}

// ---------------- BT-form bf16 GEMM ----------------
// C[m][n] = sum_k A[m][k] * Bt[n][k] + bias[n]
// 128x128 tile, BK=64, 4 waves (2x2 of 64x64), mfma_f32_16x16x32_bf16.
// LDS is fragment-major: frag f = kk*8 + mt, 1KB each; lane l owns bytes [16l,16l+16).
// SMODE: 0 = bf16 row-major, 1 = bf16 transposed-per-batch (for V^T), 2 = fp32 row-major.
template<int SMODE>
__global__ __launch_bounds__(256)
void gemm_bt(const bf16* __restrict__ A, const bf16* __restrict__ Bt,
             const float* __restrict__ bias, void* __restrict__ Cout,
             int Kdim, int Ndim)
{
  __shared__ __attribute__((aligned(16))) bf16 As[8192];  // 16KB
  __shared__ __attribute__((aligned(16))) bf16 Bs[8192];  // 16KB
  const int tid = threadIdx.x;
  const int w  = tid >> 6, l = tid & 63;
  const int ll = l & 15,  lh = l >> 4;
  const int m0 = blockIdx.y * 128, n0 = blockIdx.x * 128;
  const int wm = w >> 1, wn = w & 1;

  floatx4 acc[4][4];
#pragma unroll
  for (int i = 0; i < 4; ++i)
#pragma unroll
    for (int j = 0; j < 4; ++j) acc[i][j] = (floatx4)0.f;

  for (int k0 = 0; k0 < Kdim; k0 += 64) {
#pragma unroll
    for (int i = 0; i < 4; ++i) {
      const int f = w * 4 + i;
      const int mt = f & 7, kk = f >> 3;
      async_ld16(A  + (size_t)(m0 + mt * 16 + ll) * Kdim + (k0 + kk * 32 + lh * 8),
                 &As[f * 512 + l * 8]);
      async_ld16(Bt + (size_t)(n0 + mt * 16 + ll) * Kdim + (k0 + kk * 32 + lh * 8),
                 &Bs[f * 512 + l * 8]);
    }
    __syncthreads();
#pragma unroll
    for (int kk = 0; kk < 2; ++kk) {
      bf16x8 af[4], bfr[4];
#pragma unroll
      for (int t = 0; t < 4; ++t) {
        af[t]  = *(const bf16x8*)&As[(kk * 8 + wm * 4 + t) * 512 + l * 8];
        bfr[t] = *(const bf16x8*)&Bs[(kk * 8 + wn * 4 + t) * 512 + l * 8];
      }
#pragma unroll
      for (int mt = 0; mt < 4; ++mt)
#pragma unroll
        for (int nt = 0; nt < 4; ++nt)
          acc[mt][nt] = __builtin_amdgcn_mfma_f32_16x16x32_bf16(af[mt], bfr[nt], acc[mt][nt], 0, 0, 0);
    }
    __syncthreads();
  }

  // epilogue: C/D layout col = lane&15, row = (lane>>4)*4 + reg (verified m89/m91)
#pragma unroll
  for (int mt = 0; mt < 4; ++mt) {
#pragma unroll
    for (int nt = 0; nt < 4; ++nt) {
      const int col = n0 + wn * 64 + nt * 16 + ll;
      const float bv = bias[col];
#pragma unroll
      for (int r = 0; r < 4; ++r) {
        const int row = m0 + wm * 64 + mt * 16 + lh * 4 + r;
        const float v = acc[mt][nt][r] + bv;
        if (SMODE == 0) {
          ((bf16*)Cout)[(size_t)row * Ndim + col] = (bf16)v;
        } else if (SMODE == 1) {
          const int bb = row >> 12, s = row & 4095;
          ((bf16*)Cout)[((size_t)bb * D_MODEL + col) * SEQ + s] = (bf16)v;
        } else {
          ((float*)Cout)[(size_t)row * Ndim + col] = v;
        }
      }
    }
  }
}

// ---------------- fused windowed attention ----------------
// One block per (window, batch). Phase 1: S = Qw Kw^T / 8 (full 128x128 in acc).
// Phase 2: cross-wave softmax (deferred normalization; 1/rowsum kept in LDS).
// Phase 3: O = P @ Vw via Vt (BT form), fp32 atomicAdd into the overlap accumulator.
__global__ __launch_bounds__(256)
void attn_win(const bf16* __restrict__ qb, const bf16* __restrict__ kb,
              const bf16* __restrict__ vt, float* __restrict__ accout)
{
  __shared__ __attribute__((aligned(16))) char smem[51200];
  __shared__ float redA[256];
  __shared__ float redB[256];
  __shared__ float inv[128];

  bf16* As = (bf16*)smem;              // phase 1: Q frags, 16KB
  bf16* Bs = (bf16*)(smem + 16384);    // phase 1: K frags, 16KB
  bf16* P  = (bf16*)smem;              // phase 2/3: 128 x PSTR bf16 = 34816B (aliases As/Bs)
  bf16* Vs = (bf16*)(smem + 34816);    // phase 3: Vt frags, 16KB

  const int tid = threadIdx.x;
  const int w = tid >> 6, l = tid & 63, ll = l & 15, lh = l >> 4;
  const int wm = w >> 1, wn = w & 1;
  const int wi = blockIdx.x, b = blockIdx.y;

  const bf16* Aq = qb + ((size_t)b * SEQ + wi * 64) * D_MODEL;
  const bf16* Ak = kb + ((size_t)b * SEQ + wi * 64) * D_MODEL;

  floatx4 acc[4][4];
#pragma unroll
  for (int i = 0; i < 4; ++i)
#pragma unroll
    for (int j = 0; j < 4; ++j) acc[i][j] = (floatx4)0.f;

  // ---- phase 1: S = Q K^T ----
  for (int k0 = 0; k0 < D_MODEL; k0 += 64) {
#pragma unroll
    for (int i = 0; i < 4; ++i) {
      const int f = w * 4 + i;
      const int mt = f & 7, kk = f >> 3;
      async_ld16(Aq + (size_t)(mt * 16 + ll) * D_MODEL + (k0 + kk * 32 + lh * 8),
                 &As[f * 512 + l * 8]);
      async_ld16(Ak + (size_t)(mt * 16 + ll) * D_MODEL + (k0 + kk * 32 + lh * 8),
                 &Bs[f * 512 + l * 8]);
    }
    __syncthreads();
#pragma unroll
    for (int kk = 0; kk < 2; ++kk) {
      bf16x8 af[4], bfr[4];
#pragma unroll
      for (int t = 0; t < 4; ++t) {
        af[t]  = *(const bf16x8*)&As[(kk * 8 + wm * 4 + t) * 512 + l * 8];
        bfr[t] = *(const bf16x8*)&Bs[(kk * 8 + wn * 4 + t) * 512 + l * 8];
      }
#pragma unroll
      for (int mt = 0; mt < 4; ++mt)
#pragma unroll
        for (int nt = 0; nt < 4; ++nt)
          acc[mt][nt] = __builtin_amdgcn_mfma_f32_16x16x32_bf16(af[mt], bfr[nt], acc[mt][nt], 0, 0, 0);
    }
    __syncthreads();
  }

  // ---- phase 2: softmax over rows (scale 1/sqrt(64) = 0.125) ----
#pragma unroll
  for (int mt = 0; mt < 4; ++mt)
#pragma unroll
    for (int nt = 0; nt < 4; ++nt)
#pragma unroll
      for (int r = 0; r < 4; ++r) acc[mt][nt][r] *= 0.125f;

  // per-(mt,r) row max over 4 nt (in-lane) then over the 16 low lanes
#pragma unroll
  for (int mt = 0; mt < 4; ++mt) {
#pragma unroll
    for (int r = 0; r < 4; ++r) {
      float m = fmaxf(fmaxf(acc[mt][0][r], acc[mt][1][r]),
                      fmaxf(acc[mt][2][r], acc[mt][3][r]));
      m = fmaxf(m, __shfl_xor(m, 1));
      m = fmaxf(m, __shfl_xor(m, 2));
      m = fmaxf(m, __shfl_xor(m, 4));
      m = fmaxf(m, __shfl_xor(m, 8));
      if (ll == 0) redA[wn * 128 + wm * 64 + mt * 16 + lh * 4 + r] = m;
    }
  }
  __syncthreads();

#pragma unroll
  for (int mt = 0; mt < 4; ++mt) {
#pragma unroll
    for (int r = 0; r < 4; ++r) {
      const int row = wm * 64 + mt * 16 + lh * 4 + r;
      const float m = fmaxf(redA[row], redA[128 + row]);
#pragma unroll
      for (int nt = 0; nt < 4; ++nt)
        acc[mt][nt][r] = __expf(acc[mt][nt][r] - m);
      float s = acc[mt][0][r] + acc[mt][1][r] + acc[mt][2][r] + acc[mt][3][r];
      s += __shfl_xor(s, 1);
      s += __shfl_xor(s, 2);
      s += __shfl_xor(s, 4);
      s += __shfl_xor(s, 8);
      if (ll == 0) redB[wn * 128 + row] = s;
    }
  }
  __syncthreads();

  if (wn == 0 && ll == 0) {
#pragma unroll
    for (int mt = 0; mt < 4; ++mt)
#pragma unroll
      for (int r = 0; r < 4; ++r) {
        const int row = wm * 64 + mt * 16 + lh * 4 + r;
        inv[row] = 1.f / (redB[row] + redB[128 + row]);
      }
  }
  // write P (unnormalized exp) as bf16, row-major with pad
#pragma unroll
  for (int mt = 0; mt < 4; ++mt)
#pragma unroll
    for (int nt = 0; nt < 4; ++nt)
#pragma unroll
      for (int r = 0; r < 4; ++r)
        P[(wm * 64 + mt * 16 + lh * 4 + r) * PSTR + wn * 64 + nt * 16 + ll] =
            (bf16)acc[mt][nt][r];
  __syncthreads();

  // ---- phase 3: O = P @ V, via Vt[d][s] (BT form), 16 n-chunks of 64 d ----
  const bf16* Vtw = vt + (size_t)b * D_MODEL * SEQ + wi * 64;
  float* outp = accout + ((size_t)b * SEQ + wi * 64) * D_MODEL;

  for (int n0 = 0; n0 < D_MODEL; n0 += 64) {
#pragma unroll
    for (int i = 0; i < 4; ++i) {
      const int f = w * 4 + i;
      const int nt = f & 3, kk = f >> 2;
      async_ld16(Vtw + (size_t)(n0 + nt * 16 + ll) * SEQ + (kk * 32 + lh * 8),
                 &Vs[f * 512 + l * 8]);
    }
    __syncthreads();

    floatx4 oacc[2][4];
#pragma unroll
    for (int i = 0; i < 2; ++i)
#pragma unroll
      for (int j = 0; j < 4; ++j) oacc[i][j] = (floatx4)0.f;

#pragma unroll
    for (int kk = 0; kk < 4; ++kk) {
      bf16x8 af[2], bfr[4];
#pragma unroll
      for (int t = 0; t < 2; ++t)
        af[t] = *(const bf16x8*)&P[((w * 2 + t) * 16 + ll) * PSTR + kk * 32 + lh * 8];
#pragma unroll
      for (int t = 0; t < 4; ++t)
        bfr[t] = *(const bf16x8*)&Vs[(kk * 4 + t) * 512 + l * 8];
#pragma unroll
      for (int mt = 0; mt < 2; ++mt)
#pragma unroll
        for (int nt = 0; nt < 4; ++nt)
          oacc[mt][nt] = __builtin_amdgcn_mfma_f32_16x16x32_bf16(af[mt], bfr[nt], oacc[mt][nt], 0, 0, 0);
    }

#pragma unroll
    for (int mt = 0; mt < 2; ++mt)
#pragma unroll
      for (int nt = 0; nt < 4; ++nt)
#pragma unroll
        for (int r = 0; r < 4; ++r) {
          const int row = (w * 2 + mt) * 16 + lh * 4 + r;
          const int col = n0 + nt * 16 + ll;
          atomicAdd(&outp[(size_t)row * D_MODEL + col], oacc[mt][nt][r] * inv[row]);
        }
    __syncthreads();
  }
}

// ---------------- combine: divide by overlap count, cast to bf16 ----------------
__global__ __launch_bounds__(256)
void combine_k(const float* __restrict__ acc, bf16* __restrict__ ab)
{
  const int i = blockIdx.x * 256 + threadIdx.x;   // exactly 4M threads
  const float4 v = ((const float4*)acc)[i];
  const int s = (i >> 8) & 4095;                   // seq position
  const float f = (s < 64 || s >= 4032) ? 1.f : 0.5f;
  bf16x4 o = { (bf16)(v.x * f), (bf16)(v.y * f), (bf16)(v.z * f), (bf16)(v.w * f) };
  ((bf16x4*)ab)[i] = o;
}

// ---------------- launcher ----------------
extern "C" void kernel_launch(void* const* d_in, const int* in_sizes, int n_in,
                              void* d_out, int out_size, void* d_ws, size_t ws_size,
                              hipStream_t stream)
{
  (void)in_sizes; (void)n_in; (void)out_size;

  const float* x  = (const float*)d_in[0];
  const float* Wq = (const float*)d_in[1];
  const float* bq = (const float*)d_in[2];
  const float* Wk = (const float*)d_in[3];
  const float* bk = (const float*)d_in[4];
  const float* Wv = (const float*)d_in[5];
  const float* bv = (const float*)d_in[6];
  const float* Wo = (const float*)d_in[7];
  const float* bo = (const float*)d_in[8];

  // workspace layout (bytes): xb 32M | wt 8M | qb 32M | kb 32M | vt 32M | ab 32M = 168 MiB
  if (ws_size < (size_t)176160768) return;  // diagnosable failure if ws is too small
  char* ws = (char*)d_ws;
  bf16* xb = (bf16*)(ws);
  bf16* wt = (bf16*)(ws + 33554432);
  bf16* qb = (bf16*)(ws + 41943040);
  bf16* kb = (bf16*)(ws + 75497472);
  bf16* vt = (bf16*)(ws + 109051904);
  bf16* ab = (bf16*)(ws + 142606336);
  float* accb = (float*)d_out;   // fp32 overlap accumulator lives in d_out until final GEMM

  cvt_x_kernel<<<16384, 256, 0, stream>>>(x, xb);
  cvt_wt_kernel<<<dim3(32, 32, 4), 256, 0, stream>>>(Wq, Wk, Wv, Wo, wt);

  gemm_bt<0><<<dim3(8, 128), 256, 0, stream>>>(xb, wt,           bq, qb, D_MODEL, D_MODEL);
  gemm_bt<0><<<dim3(8, 128), 256, 0, stream>>>(xb, wt + 1048576, bk, kb, D_MODEL, D_MODEL);
  gemm_bt<1><<<dim3(8, 128), 256, 0, stream>>>(xb, wt + 2097152, bv, vt, D_MODEL, D_MODEL);

  hipMemsetAsync(d_out, 0, (size_t)MTOT * D_MODEL * sizeof(float), stream);
  attn_win<<<dim3(NWIN, BATCH), 256, 0, stream>>>(qb, kb, vt, accb);
  combine_k<<<16384, 256, 0, stream>>>(accb, ab);

  gemm_bt<2><<<dim3(8, 128), 256, 0, stream>>>(ab, wt + 3145728, bo, d_out, D_MODEL, D_MODEL);
}

// Round 2
// 519.196 us; speedup vs baseline: 1.1714x; 1.1714x over previous
//
#include <hip/hip_runtime.h>
#include <stdint.h>
#include <stddef.h>

#define D_MODEL 1024
#define SEQ     4096
#define BATCH   4
#define MTOT    (BATCH*SEQ)     // 16384
#define NWIN    63

typedef __bf16 bf16;
typedef __bf16 bf16x8 __attribute__((ext_vector_type(8)));
typedef __bf16 bf16x4 __attribute__((ext_vector_type(4)));
typedef float  floatx4 __attribute__((ext_vector_type(4)));

// async global->LDS, 16B per lane. LDS dest is wave-uniform base + lane*16.
__device__ __forceinline__ void async_ld16(const void* g, void* l) {
  __builtin_amdgcn_global_load_lds(
      (const __attribute__((address_space(1))) unsigned int*)g,
      (__attribute__((address_space(3))) unsigned int*)l,
      16, 0, 0);
}

// ---------------- elementwise converts ----------------

__global__ __launch_bounds__(256)
void cvt_x_kernel(const float* __restrict__ x, bf16* __restrict__ xb)
{
  const int i = blockIdx.x * 256 + threadIdx.x;   // exactly 4M threads (16M elems /4)
  const float4 v = ((const float4*)x)[i];
  bf16x4 o = { (bf16)v.x, (bf16)v.y, (bf16)v.z, (bf16)v.w };
  ((bf16x4*)xb)[i] = o;
}

// W (fp32, [K][N]) -> Wt (bf16, [N][K]) for 4 weight matrices (blockIdx.z selects)
__global__ __launch_bounds__(256)
void cvt_wt_kernel(const float* __restrict__ W0, const float* __restrict__ W1,
                   const float* __restrict__ W2, const float* __restrict__ W3,
                   bf16* __restrict__ wt)
{
  __shared__ float tile[32][33];
  const float* Wsel = (blockIdx.z == 0) ? W0 : (blockIdx.z == 1) ? W1
                    : (blockIdx.z == 2) ? W2 : W3;
  bf16* Wt = wt + (size_t)blockIdx.z * D_MODEL * D_MODEL;
  const int tx = threadIdx.x & 31, ty = threadIdx.x >> 5;  // 32 x 8
  const int tn = blockIdx.x * 32, tk = blockIdx.y * 32;
#pragma unroll
  for (int j = 0; j < 32; j += 8)
    tile[ty + j][tx] = Wsel[(size_t)(tk + ty + j) * D_MODEL + (tn + tx)];
  __syncthreads();
#pragma unroll
  for (int j = 0; j < 32; j += 8)
    Wt[(size_t)(tn + ty + j) * D_MODEL + (tk + tx)] = (bf16)tile[tx][ty + j];
}

// ---------------- BT-form bf16 GEMM ----------------
// C[m][n] = sum_k A[m][k] * Bt[n][k] + bias[n]
// 128x128 tile, BK=64, 4 waves (2x2 of 64x64), mfma_f32_16x16x32_bf16.
// LDS is fragment-major: frag f = kk*8 + mt, 1KB each; lane l owns bytes [16l,16l+16).
// SMODE: 0 = bf16 row-major, 1 = bf16 transposed-per-batch (for V^T), 2 = fp32 row-major.
template<int SMODE>
__global__ __launch_bounds__(256)
void gemm_bt(const bf16* __restrict__ A, const bf16* __restrict__ Bt,
             const float* __restrict__ bias, void* __restrict__ Cout,
             int Kdim, int Ndim)
{
  __shared__ __attribute__((aligned(16))) bf16 As[8192];  // 16KB
  __shared__ __attribute__((aligned(16))) bf16 Bs[8192];  // 16KB
  const int tid = threadIdx.x;
  const int w  = tid >> 6, l = tid & 63;
  const int ll = l & 15,  lh = l >> 4;
  const int m0 = blockIdx.y * 128, n0 = blockIdx.x * 128;
  const int wm = w >> 1, wn = w & 1;

  floatx4 acc[4][4];
#pragma unroll
  for (int i = 0; i < 4; ++i)
#pragma unroll
    for (int j = 0; j < 4; ++j) acc[i][j] = (floatx4)0.f;

  for (int k0 = 0; k0 < Kdim; k0 += 64) {
#pragma unroll
    for (int i = 0; i < 4; ++i) {
      const int f = w * 4 + i;
      const int mt = f & 7, kk = f >> 3;
      async_ld16(A  + (size_t)(m0 + mt * 16 + ll) * Kdim + (k0 + kk * 32 + lh * 8),
                 &As[f * 512 + l * 8]);
      async_ld16(Bt + (size_t)(n0 + mt * 16 + ll) * Kdim + (k0 + kk * 32 + lh * 8),
                 &Bs[f * 512 + l * 8]);
    }
    __syncthreads();
#pragma unroll
    for (int kk = 0; kk < 2; ++kk) {
      bf16x8 af[4], bfr[4];
#pragma unroll
      for (int t = 0; t < 4; ++t) {
        af[t]  = *(const bf16x8*)&As[(kk * 8 + wm * 4 + t) * 512 + l * 8];
        bfr[t] = *(const bf16x8*)&Bs[(kk * 8 + wn * 4 + t) * 512 + l * 8];
      }
#pragma unroll
      for (int mt = 0; mt < 4; ++mt)
#pragma unroll
        for (int nt = 0; nt < 4; ++nt)
          acc[mt][nt] = __builtin_amdgcn_mfma_f32_16x16x32_bf16(af[mt], bfr[nt], acc[mt][nt], 0, 0, 0);
    }
    __syncthreads();
  }

  // epilogue: C/D layout col = lane&15, row = (lane>>4)*4 + reg (verified m89/m91)
#pragma unroll
  for (int mt = 0; mt < 4; ++mt) {
#pragma unroll
    for (int nt = 0; nt < 4; ++nt) {
      const int col = n0 + wn * 64 + nt * 16 + ll;
      const float bv = bias[col];
#pragma unroll
      for (int r = 0; r < 4; ++r) {
        const int row = m0 + wm * 64 + mt * 16 + lh * 4 + r;
        const float v = acc[mt][nt][r] + bv;
        if (SMODE == 0) {
          ((bf16*)Cout)[(size_t)row * Ndim + col] = (bf16)v;
        } else if (SMODE == 1) {
          const int bb = row >> 12, s = row & 4095;
          ((bf16*)Cout)[((size_t)bb * D_MODEL + col) * SEQ + s] = (bf16)v;
        } else {
          ((float*)Cout)[(size_t)row * Ndim + col] = v;
        }
      }
    }
  }
}

// ---------------- kernel A: QK^T + softmax -> normalized P (bf16) ----------------
// One block per (q-half, window, batch): 64 q rows x 128 keys, K=1024 contraction.
// Waves split the 128 keys into 4 chunks of 32 (acc[4][2] each). Softmax is fully
// local (whole key row in-block). P stored normalized, row-major 128 stride:
// P[b][win][128 q][128 k].
__global__ __launch_bounds__(256)
void qk_softmax(const bf16* __restrict__ qb, const bf16* __restrict__ kb,
                bf16* __restrict__ Pg)
{
  __shared__ __attribute__((aligned(16))) bf16 As[4096];   // Q 64x64, 8KB
  __shared__ __attribute__((aligned(16))) bf16 Bs[8192];   // K 128x64, 16KB
  __shared__ float redM[4][64];
  __shared__ float redS[4][64];

  const int tid = threadIdx.x;
  const int w = tid >> 6, l = tid & 63, ll = l & 15, lh = l >> 4;
  const int wh = blockIdx.x;                 // 0..125
  const int win = wh >> 1, half = wh & 1;
  const int b = blockIdx.y;

  const bf16* Aq = qb + ((size_t)b * SEQ + win * 64 + half * 64) * D_MODEL;
  const bf16* Ak = kb + ((size_t)b * SEQ + win * 64) * D_MODEL;

  floatx4 acc[4][2];
#pragma unroll
  for (int i = 0; i < 4; ++i)
#pragma unroll
    for (int j = 0; j < 2; ++j) acc[i][j] = (floatx4)0.f;

  for (int c0 = 0; c0 < D_MODEL; c0 += 64) {
#pragma unroll
    for (int i = 0; i < 2; ++i) {            // Q: 8 frags (4 m x 2 kk)
      const int f = w * 2 + i;
      const int mt = f & 3, kk = f >> 2;
      async_ld16(Aq + (size_t)(mt * 16 + ll) * D_MODEL + (c0 + kk * 32 + lh * 8),
                 &As[f * 512 + l * 8]);
    }
#pragma unroll
    for (int i = 0; i < 4; ++i) {            // K: 16 frags (8 n x 2 kk)
      const int f = w * 4 + i;
      const int mt = f & 7, kk = f >> 3;
      async_ld16(Ak + (size_t)(mt * 16 + ll) * D_MODEL + (c0 + kk * 32 + lh * 8),
                 &Bs[f * 512 + l * 8]);
    }
    __syncthreads();
#pragma unroll
    for (int kk = 0; kk < 2; ++kk) {
      bf16x8 af[4], bfr[2];
#pragma unroll
      for (int t = 0; t < 4; ++t)
        af[t]  = *(const bf16x8*)&As[(kk * 4 + t) * 512 + l * 8];
#pragma unroll
      for (int t = 0; t < 2; ++t)
        bfr[t] = *(const bf16x8*)&Bs[(kk * 8 + w * 2 + t) * 512 + l * 8];
#pragma unroll
      for (int mt = 0; mt < 4; ++mt)
#pragma unroll
        for (int nt = 0; nt < 2; ++nt)
          acc[mt][nt] = __builtin_amdgcn_mfma_f32_16x16x32_bf16(af[mt], bfr[nt], acc[mt][nt], 0, 0, 0);
    }
    __syncthreads();
  }

  // scale by 1/sqrt(HEAD_DIM)=0.125
#pragma unroll
  for (int mt = 0; mt < 4; ++mt)
#pragma unroll
    for (int nt = 0; nt < 2; ++nt)
#pragma unroll
      for (int r = 0; r < 4; ++r) acc[mt][nt][r] *= 0.125f;

  // row max: in-lane over 2 nt, shuffle over 16 cols, LDS across 4 waves
#pragma unroll
  for (int mt = 0; mt < 4; ++mt)
#pragma unroll
    for (int r = 0; r < 4; ++r) {
      float m = fmaxf(acc[mt][0][r], acc[mt][1][r]);
      m = fmaxf(m, __shfl_xor(m, 1));
      m = fmaxf(m, __shfl_xor(m, 2));
      m = fmaxf(m, __shfl_xor(m, 4));
      m = fmaxf(m, __shfl_xor(m, 8));
      if (ll == 0) redM[w][mt * 16 + lh * 4 + r] = m;
    }
  __syncthreads();

#pragma unroll
  for (int mt = 0; mt < 4; ++mt)
#pragma unroll
    for (int r = 0; r < 4; ++r) {
      const int row = mt * 16 + lh * 4 + r;
      const float m = fmaxf(fmaxf(redM[0][row], redM[1][row]),
                            fmaxf(redM[2][row], redM[3][row]));
      const float e0 = __expf(acc[mt][0][r] - m);
      const float e1 = __expf(acc[mt][1][r] - m);
      acc[mt][0][r] = e0; acc[mt][1][r] = e1;
      float s = e0 + e1;
      s += __shfl_xor(s, 1);
      s += __shfl_xor(s, 2);
      s += __shfl_xor(s, 4);
      s += __shfl_xor(s, 8);
      if (ll == 0) redS[w][row] = s;
    }
  __syncthreads();

  bf16* Pb = Pg + ((size_t)(b * NWIN + win) * 128 + half * 64) * 128;
#pragma unroll
  for (int mt = 0; mt < 4; ++mt)
#pragma unroll
    for (int r = 0; r < 4; ++r) {
      const int row = mt * 16 + lh * 4 + r;
      const float inv = 1.f / (redS[0][row] + redS[1][row] + redS[2][row] + redS[3][row]);
#pragma unroll
      for (int nt = 0; nt < 2; ++nt)
        Pb[(size_t)row * 128 + w * 32 + nt * 16 + ll] = (bf16)(acc[mt][nt][r] * inv);
    }
}

// ---------------- kernel B: gather-form P@V, averaged, direct bf16 store ----------
// One block per (d-chunk, seq-chunk, batch). Seq chunk h (64 rows) gets contributions
// from window h-1 (its rows 64..127) and window h (rows 0..63); K=256 total.
// No atomics: scale by 1/count and write bf16 straight into ab.
__global__ __launch_bounds__(256)
void pv_gather(const bf16* __restrict__ Pg, const bf16* __restrict__ vt,
               bf16* __restrict__ ab)
{
  __shared__ __attribute__((aligned(16))) bf16 As[4096];   // P 64x64, 8KB
  __shared__ __attribute__((aligned(16))) bf16 Bs[8192];   // Vt 128x64, 16KB

  const int tid = threadIdx.x;
  const int w = tid >> 6, l = tid & 63, ll = l & 15, lh = l >> 4;
  const int d0 = blockIdx.x * 128;           // 0..7
  const int h  = blockIdx.y;                 // 0..63
  const int b  = blockIdx.z;

  int wseg[2], roff[2];
  int nseg = 0;
  if (h >= 1)        { wseg[nseg] = h - 1; roff[nseg] = 64; ++nseg; }
  if (h <= NWIN - 1) { wseg[nseg] = h;     roff[nseg] = 0;  ++nseg; }
  const float scale = (nseg == 2) ? 0.5f : 1.0f;

  floatx4 acc[4][2];
#pragma unroll
  for (int i = 0; i < 4; ++i)
#pragma unroll
    for (int j = 0; j < 2; ++j) acc[i][j] = (floatx4)0.f;

  for (int sg = 0; sg < nseg; ++sg) {
    const bf16* Pseg = Pg + ((size_t)(b * NWIN + wseg[sg]) * 128 + roff[sg]) * 128;
    const bf16* Vseg = vt + ((size_t)b * D_MODEL + d0) * SEQ + wseg[sg] * 64;
    for (int c0 = 0; c0 < 128; c0 += 64) {
#pragma unroll
      for (int i = 0; i < 2; ++i) {          // P: 8 frags (4 m x 2 kk)
        const int f = w * 2 + i;
        const int mt = f & 3, kk = f >> 2;
        async_ld16(Pseg + (size_t)(mt * 16 + ll) * 128 + (c0 + kk * 32 + lh * 8),
                   &As[f * 512 + l * 8]);
      }
#pragma unroll
      for (int i = 0; i < 4; ++i) {          // Vt: 16 frags (8 n x 2 kk)
        const int f = w * 4 + i;
        const int mt = f & 7, kk = f >> 3;
        async_ld16(Vseg + (size_t)(mt * 16 + ll) * SEQ + (c0 + kk * 32 + lh * 8),
                   &Bs[f * 512 + l * 8]);
      }
      __syncthreads();
#pragma unroll
      for (int kk = 0; kk < 2; ++kk) {
        bf16x8 af[4], bfr[2];
#pragma unroll
        for (int t = 0; t < 4; ++t)
          af[t]  = *(const bf16x8*)&As[(kk * 4 + t) * 512 + l * 8];
#pragma unroll
        for (int t = 0; t < 2; ++t)
          bfr[t] = *(const bf16x8*)&Bs[(kk * 8 + w * 2 + t) * 512 + l * 8];
#pragma unroll
        for (int mt = 0; mt < 4; ++mt)
#pragma unroll
          for (int nt = 0; nt < 2; ++nt)
            acc[mt][nt] = __builtin_amdgcn_mfma_f32_16x16x32_bf16(af[mt], bfr[nt], acc[mt][nt], 0, 0, 0);
      }
      __syncthreads();
    }
  }

#pragma unroll
  for (int mt = 0; mt < 4; ++mt)
#pragma unroll
    for (int nt = 0; nt < 2; ++nt)
#pragma unroll
      for (int r = 0; r < 4; ++r) {
        const int row = h * 64 + mt * 16 + lh * 4 + r;
        const int col = d0 + w * 32 + nt * 16 + ll;
        ab[((size_t)b * SEQ + row) * D_MODEL + col] = (bf16)(acc[mt][nt][r] * scale);
      }
}

// ---------------- launcher ----------------
extern "C" void kernel_launch(void* const* d_in, const int* in_sizes, int n_in,
                              void* d_out, int out_size, void* d_ws, size_t ws_size,
                              hipStream_t stream)
{
  (void)in_sizes; (void)n_in; (void)out_size;

  const float* x  = (const float*)d_in[0];
  const float* Wq = (const float*)d_in[1];
  const float* bq = (const float*)d_in[2];
  const float* Wk = (const float*)d_in[3];
  const float* bk = (const float*)d_in[4];
  const float* Wv = (const float*)d_in[5];
  const float* bv = (const float*)d_in[6];
  const float* Wo = (const float*)d_in[7];
  const float* bo = (const float*)d_in[8];

  // workspace layout (bytes): xb 32M | wt 8M | qb 32M | kb 32M | vt 32M | ab 32M = 168 MiB
  // P (8.26 MB) aliases xb: xb's last use is gemm_bt<1>, P's first write is after.
  if (ws_size < (size_t)176160768) return;
  char* ws = (char*)d_ws;
  bf16* xb = (bf16*)(ws);
  bf16* pb = (bf16*)(ws);                  // P[b][win][128][128] bf16, aliases xb
  bf16* wt = (bf16*)(ws + 33554432);
  bf16* qb = (bf16*)(ws + 41943040);
  bf16* kb = (bf16*)(ws + 75497472);
  bf16* vt = (bf16*)(ws + 109051904);
  bf16* ab = (bf16*)(ws + 142606336);

  cvt_x_kernel<<<16384, 256, 0, stream>>>(x, xb);
  cvt_wt_kernel<<<dim3(32, 32, 4), 256, 0, stream>>>(Wq, Wk, Wv, Wo, wt);

  gemm_bt<0><<<dim3(8, 128), 256, 0, stream>>>(xb, wt,           bq, qb, D_MODEL, D_MODEL);
  gemm_bt<0><<<dim3(8, 128), 256, 0, stream>>>(xb, wt + 1048576, bk, kb, D_MODEL, D_MODEL);
  gemm_bt<1><<<dim3(8, 128), 256, 0, stream>>>(xb, wt + 2097152, bv, vt, D_MODEL, D_MODEL);

  qk_softmax<<<dim3(126, BATCH), 256, 0, stream>>>(qb, kb, pb);
  pv_gather<<<dim3(8, 64, BATCH), 256, 0, stream>>>(pb, vt, ab);

  gemm_bt<2><<<dim3(8, 128), 256, 0, stream>>>(ab, wt + 3145728, bo, (float*)d_out, D_MODEL, D_MODEL);
}

// Round 3
// 498.610 us; speedup vs baseline: 1.2197x; 1.0413x over previous
//
#include <hip/hip_runtime.h>
#include <stdint.h>
#include <stddef.h>

#define D_MODEL 1024
#define SEQ     4096
#define BATCH   4
#define MTOT    (BATCH*SEQ)     // 16384
#define NWIN    63

typedef __bf16 bf16;
typedef __bf16 bf16x8 __attribute__((ext_vector_type(8)));
typedef __bf16 bf16x4 __attribute__((ext_vector_type(4)));
typedef float  floatx4 __attribute__((ext_vector_type(4)));

// async global->LDS, 16B per lane. LDS dest is wave-uniform base + lane*16.
__device__ __forceinline__ void async_ld16(const void* g, void* l) {
  __builtin_amdgcn_global_load_lds(
      (const __attribute__((address_space(1))) unsigned int*)g,
      (__attribute__((address_space(3))) unsigned int*)l,
      16, 0, 0);
}

// ---------------- elementwise converts ----------------

__global__ __launch_bounds__(256)
void cvt_x_kernel(const float* __restrict__ x, bf16* __restrict__ xb)
{
  const int i = blockIdx.x * 256 + threadIdx.x;   // exactly 4M threads (16M elems /4)
  const float4 v = ((const float4*)x)[i];
  bf16x4 o = { (bf16)v.x, (bf16)v.y, (bf16)v.z, (bf16)v.w };
  ((bf16x4*)xb)[i] = o;
}

// W (fp32, [K][N]) -> Wt (bf16, [N][K]) for 4 weight matrices (blockIdx.z selects).
// Packed contiguously: rows 0..1023 = Wq^T, 1024..2047 = Wk^T, 2048..3071 = Wv^T,
// 3072..4095 = Wo^T -- so the fused QKV GEMM can use rows 0..3071 directly.
__global__ __launch_bounds__(256)
void cvt_wt_kernel(const float* __restrict__ W0, const float* __restrict__ W1,
                   const float* __restrict__ W2, const float* __restrict__ W3,
                   bf16* __restrict__ wt)
{
  __shared__ float tile[32][33];
  const float* Wsel = (blockIdx.z == 0) ? W0 : (blockIdx.z == 1) ? W1
                    : (blockIdx.z == 2) ? W2 : W3;
  bf16* Wt = wt + (size_t)blockIdx.z * D_MODEL * D_MODEL;
  const int tx = threadIdx.x & 31, ty = threadIdx.x >> 5;  // 32 x 8
  const int tn = blockIdx.x * 32, tk = blockIdx.y * 32;
#pragma unroll
  for (int j = 0; j < 32; j += 8)
    tile[ty + j][tx] = Wsel[(size_t)(tk + ty + j) * D_MODEL + (tn + tx)];
  __syncthreads();
#pragma unroll
  for (int j = 0; j < 32; j += 8)
    Wt[(size_t)(tn + ty + j) * D_MODEL + (tk + tx)] = (bf16)tile[tx][ty + j];
}

// ---------------- shared GEMM core ----------------
// 128x128 tile, BK=64, 4 waves (2x2 of 64x64), mfma_f32_16x16x32_bf16, BT form.
// LDS fragment-major: frag f, 1KB each; lane l owns bytes [16l,16l+16).
__device__ __forceinline__ void gemm_core(const bf16* __restrict__ A,
                                          const bf16* __restrict__ Bt,
                                          int Kdim, int m0, int n0,
                                          bf16* As, bf16* Bs,
                                          floatx4 (&acc)[4][4],
                                          int w, int l)
{
  const int ll = l & 15, lh = l >> 4;
  const int wm = w >> 1, wn = w & 1;

  for (int k0 = 0; k0 < Kdim; k0 += 64) {
#pragma unroll
    for (int i = 0; i < 4; ++i) {
      const int f = w * 4 + i;
      const int mt = f & 7, kk = f >> 3;
      async_ld16(A  + (size_t)(m0 + mt * 16 + ll) * Kdim + (k0 + kk * 32 + lh * 8),
                 &As[f * 512 + l * 8]);
      async_ld16(Bt + (size_t)(n0 + mt * 16 + ll) * Kdim + (k0 + kk * 32 + lh * 8),
                 &Bs[f * 512 + l * 8]);
    }
    __syncthreads();
#pragma unroll
    for (int kk = 0; kk < 2; ++kk) {
      bf16x8 af[4], bfr[4];
#pragma unroll
      for (int t = 0; t < 4; ++t) {
        af[t]  = *(const bf16x8*)&As[(kk * 8 + wm * 4 + t) * 512 + l * 8];
        bfr[t] = *(const bf16x8*)&Bs[(kk * 8 + wn * 4 + t) * 512 + l * 8];
      }
#pragma unroll
      for (int mt = 0; mt < 4; ++mt)
#pragma unroll
        for (int nt = 0; nt < 4; ++nt)
          acc[mt][nt] = __builtin_amdgcn_mfma_f32_16x16x32_bf16(af[mt], bfr[nt], acc[mt][nt], 0, 0, 0);
    }
    __syncthreads();
  }
}

// ---------------- fused QKV projection GEMM ----------------
// C[16384][3072] = xb @ [Wq|Wk|Wv] + [bq|bk|bv]; n<1024 -> qb, <2048 -> kb,
// else -> vt (transposed per batch). Grid 3072 1-D, XCD-swizzled:
// xcd owns m-blocks [xcd*16, xcd*16+16) (A-chunk ~4MB, L2-resident),
// m fastest within the chunk so 16 consecutive blocks share one B-tile.
__global__ __launch_bounds__(256)
void gemm_qkv(const bf16* __restrict__ A, const bf16* __restrict__ Bt,
              const float* __restrict__ bq, const float* __restrict__ bk,
              const float* __restrict__ bv,
              bf16* __restrict__ qo, bf16* __restrict__ ko, bf16* __restrict__ vto)
{
  __shared__ __attribute__((aligned(16))) bf16 As[8192];  // 16KB
  __shared__ __attribute__((aligned(16))) bf16 Bs[8192];  // 16KB
  const int tid = threadIdx.x;
  const int w = tid >> 6, l = tid & 63;
  const int ll = l & 15, lh = l >> 4;
  const int wm = w >> 1, wn = w & 1;

  const int idx = blockIdx.x;            // 0..3071
  const int xcd = idx & 7;
  const int local = idx >> 3;            // 0..383
  const int mblk = xcd * 16 + (local & 15);
  const int nblk = local >> 4;           // 0..23
  const int m0 = mblk * 128, n0 = nblk * 128;

  floatx4 acc[4][4];
#pragma unroll
  for (int i = 0; i < 4; ++i)
#pragma unroll
    for (int j = 0; j < 4; ++j) acc[i][j] = (floatx4)0.f;

  gemm_core(A, Bt, D_MODEL, m0, n0, As, Bs, acc, w, l);

  const int sel = n0 >> 10;              // 0=q 1=k 2=v (block-uniform)
  const int ncl = n0 & 1023;             // column base within the 1024-wide output
  const float* bias = (sel == 0) ? bq : (sel == 1) ? bk : bv;

#pragma unroll
  for (int mt = 0; mt < 4; ++mt) {
#pragma unroll
    for (int nt = 0; nt < 4; ++nt) {
      const int colL = ncl + wn * 64 + nt * 16 + ll;
      const float bvv = bias[colL];
#pragma unroll
      for (int r = 0; r < 4; ++r) {
        const int row = m0 + wm * 64 + mt * 16 + lh * 4 + r;
        const float v = acc[mt][nt][r] + bvv;
        if (sel == 0) {
          qo[(size_t)row * D_MODEL + colL] = (bf16)v;
        } else if (sel == 1) {
          ko[(size_t)row * D_MODEL + colL] = (bf16)v;
        } else {
          const int bb = row >> 12, s = row & 4095;
          vto[((size_t)bb * D_MODEL + colL) * SEQ + s] = (bf16)v;
        }
      }
    }
  }
}

// ---------------- output projection GEMM (fp32 out) ----------------
// Same swizzle; 8 n-blocks.
__global__ __launch_bounds__(256)
void gemm_out(const bf16* __restrict__ A, const bf16* __restrict__ Bt,
              const float* __restrict__ bias, float* __restrict__ C)
{
  __shared__ __attribute__((aligned(16))) bf16 As[8192];
  __shared__ __attribute__((aligned(16))) bf16 Bs[8192];
  const int tid = threadIdx.x;
  const int w = tid >> 6, l = tid & 63;
  const int ll = l & 15, lh = l >> 4;
  const int wm = w >> 1, wn = w & 1;

  const int idx = blockIdx.x;            // 0..1023
  const int xcd = idx & 7;
  const int local = idx >> 3;            // 0..127
  const int mblk = xcd * 16 + (local & 15);
  const int nblk = local >> 4;           // 0..7
  const int m0 = mblk * 128, n0 = nblk * 128;

  floatx4 acc[4][4];
#pragma unroll
  for (int i = 0; i < 4; ++i)
#pragma unroll
    for (int j = 0; j < 4; ++j) acc[i][j] = (floatx4)0.f;

  gemm_core(A, Bt, D_MODEL, m0, n0, As, Bs, acc, w, l);

#pragma unroll
  for (int mt = 0; mt < 4; ++mt) {
#pragma unroll
    for (int nt = 0; nt < 4; ++nt) {
      const int col = n0 + wn * 64 + nt * 16 + ll;
      const float bvv = bias[col];
#pragma unroll
      for (int r = 0; r < 4; ++r) {
        const int row = m0 + wm * 64 + mt * 16 + lh * 4 + r;
        C[(size_t)row * D_MODEL + col] = acc[mt][nt][r] + bvv;
      }
    }
  }
}

// ---------------- kernel A: QK^T + softmax -> normalized P (bf16) ----------------
// One block per (q-half, window, batch): 64 q rows x 128 keys, K=1024 contraction.
__global__ __launch_bounds__(256)
void qk_softmax(const bf16* __restrict__ qb, const bf16* __restrict__ kb,
                bf16* __restrict__ Pg)
{
  __shared__ __attribute__((aligned(16))) bf16 As[4096];   // Q 64x64, 8KB
  __shared__ __attribute__((aligned(16))) bf16 Bs[8192];   // K 128x64, 16KB
  __shared__ float redM[4][64];
  __shared__ float redS[4][64];

  const int tid = threadIdx.x;
  const int w = tid >> 6, l = tid & 63, ll = l & 15, lh = l >> 4;
  const int wh = blockIdx.x;                 // 0..125
  const int win = wh >> 1, half = wh & 1;
  const int b = blockIdx.y;

  const bf16* Aq = qb + ((size_t)b * SEQ + win * 64 + half * 64) * D_MODEL;
  const bf16* Ak = kb + ((size_t)b * SEQ + win * 64) * D_MODEL;

  floatx4 acc[4][2];
#pragma unroll
  for (int i = 0; i < 4; ++i)
#pragma unroll
    for (int j = 0; j < 2; ++j) acc[i][j] = (floatx4)0.f;

  for (int c0 = 0; c0 < D_MODEL; c0 += 64) {
#pragma unroll
    for (int i = 0; i < 2; ++i) {            // Q: 8 frags (4 m x 2 kk)
      const int f = w * 2 + i;
      const int mt = f & 3, kk = f >> 2;
      async_ld16(Aq + (size_t)(mt * 16 + ll) * D_MODEL + (c0 + kk * 32 + lh * 8),
                 &As[f * 512 + l * 8]);
    }
#pragma unroll
    for (int i = 0; i < 4; ++i) {            // K: 16 frags (8 n x 2 kk)
      const int f = w * 4 + i;
      const int mt = f & 7, kk = f >> 3;
      async_ld16(Ak + (size_t)(mt * 16 + ll) * D_MODEL + (c0 + kk * 32 + lh * 8),
                 &Bs[f * 512 + l * 8]);
    }
    __syncthreads();
#pragma unroll
    for (int kk = 0; kk < 2; ++kk) {
      bf16x8 af[4], bfr[2];
#pragma unroll
      for (int t = 0; t < 4; ++t)
        af[t]  = *(const bf16x8*)&As[(kk * 4 + t) * 512 + l * 8];
#pragma unroll
      for (int t = 0; t < 2; ++t)
        bfr[t] = *(const bf16x8*)&Bs[(kk * 8 + w * 2 + t) * 512 + l * 8];
#pragma unroll
      for (int mt = 0; mt < 4; ++mt)
#pragma unroll
        for (int nt = 0; nt < 2; ++nt)
          acc[mt][nt] = __builtin_amdgcn_mfma_f32_16x16x32_bf16(af[mt], bfr[nt], acc[mt][nt], 0, 0, 0);
    }
    __syncthreads();
  }

  // scale by 1/sqrt(HEAD_DIM)=0.125
#pragma unroll
  for (int mt = 0; mt < 4; ++mt)
#pragma unroll
    for (int nt = 0; nt < 2; ++nt)
#pragma unroll
      for (int r = 0; r < 4; ++r) acc[mt][nt][r] *= 0.125f;

#pragma unroll
  for (int mt = 0; mt < 4; ++mt)
#pragma unroll
    for (int r = 0; r < 4; ++r) {
      float m = fmaxf(acc[mt][0][r], acc[mt][1][r]);
      m = fmaxf(m, __shfl_xor(m, 1));
      m = fmaxf(m, __shfl_xor(m, 2));
      m = fmaxf(m, __shfl_xor(m, 4));
      m = fmaxf(m, __shfl_xor(m, 8));
      if (ll == 0) redM[w][mt * 16 + lh * 4 + r] = m;
    }
  __syncthreads();

#pragma unroll
  for (int mt = 0; mt < 4; ++mt)
#pragma unroll
    for (int r = 0; r < 4; ++r) {
      const int row = mt * 16 + lh * 4 + r;
      const float m = fmaxf(fmaxf(redM[0][row], redM[1][row]),
                            fmaxf(redM[2][row], redM[3][row]));
      const float e0 = __expf(acc[mt][0][r] - m);
      const float e1 = __expf(acc[mt][1][r] - m);
      acc[mt][0][r] = e0; acc[mt][1][r] = e1;
      float s = e0 + e1;
      s += __shfl_xor(s, 1);
      s += __shfl_xor(s, 2);
      s += __shfl_xor(s, 4);
      s += __shfl_xor(s, 8);
      if (ll == 0) redS[w][row] = s;
    }
  __syncthreads();

  bf16* Pb = Pg + ((size_t)(b * NWIN + win) * 128 + half * 64) * 128;
#pragma unroll
  for (int mt = 0; mt < 4; ++mt)
#pragma unroll
    for (int r = 0; r < 4; ++r) {
      const int row = mt * 16 + lh * 4 + r;
      const float inv = 1.f / (redS[0][row] + redS[1][row] + redS[2][row] + redS[3][row]);
#pragma unroll
      for (int nt = 0; nt < 2; ++nt)
        Pb[(size_t)row * 128 + w * 32 + nt * 16 + ll] = (bf16)(acc[mt][nt][r] * inv);
    }
}

// ---------------- kernel B: gather-form P@V, averaged, direct bf16 store ----------
__global__ __launch_bounds__(256)
void pv_gather(const bf16* __restrict__ Pg, const bf16* __restrict__ vt,
               bf16* __restrict__ ab)
{
  __shared__ __attribute__((aligned(16))) bf16 As[4096];   // P 64x64, 8KB
  __shared__ __attribute__((aligned(16))) bf16 Bs[8192];   // Vt 128x64, 16KB

  const int tid = threadIdx.x;
  const int w = tid >> 6, l = tid & 63, ll = l & 15, lh = l >> 4;
  const int d0 = blockIdx.x * 128;           // 0..7
  const int h  = blockIdx.y;                 // 0..63
  const int b  = blockIdx.z;

  int wseg[2], roff[2];
  int nseg = 0;
  if (h >= 1)        { wseg[nseg] = h - 1; roff[nseg] = 64; ++nseg; }
  if (h <= NWIN - 1) { wseg[nseg] = h;     roff[nseg] = 0;  ++nseg; }
  const float scale = (nseg == 2) ? 0.5f : 1.0f;

  floatx4 acc[4][2];
#pragma unroll
  for (int i = 0; i < 4; ++i)
#pragma unroll
    for (int j = 0; j < 2; ++j) acc[i][j] = (floatx4)0.f;

  for (int sg = 0; sg < nseg; ++sg) {
    const bf16* Pseg = Pg + ((size_t)(b * NWIN + wseg[sg]) * 128 + roff[sg]) * 128;
    const bf16* Vseg = vt + ((size_t)b * D_MODEL + d0) * SEQ + wseg[sg] * 64;
    for (int c0 = 0; c0 < 128; c0 += 64) {
#pragma unroll
      for (int i = 0; i < 2; ++i) {          // P: 8 frags (4 m x 2 kk)
        const int f = w * 2 + i;
        const int mt = f & 3, kk = f >> 2;
        async_ld16(Pseg + (size_t)(mt * 16 + ll) * 128 + (c0 + kk * 32 + lh * 8),
                   &As[f * 512 + l * 8]);
      }
#pragma unroll
      for (int i = 0; i < 4; ++i) {          // Vt: 16 frags (8 n x 2 kk)
        const int f = w * 4 + i;
        const int mt = f & 7, kk = f >> 3;
        async_ld16(Vseg + (size_t)(mt * 16 + ll) * SEQ + (c0 + kk * 32 + lh * 8),
                   &Bs[f * 512 + l * 8]);
      }
      __syncthreads();
#pragma unroll
      for (int kk = 0; kk < 2; ++kk) {
        bf16x8 af[4], bfr[2];
#pragma unroll
        for (int t = 0; t < 4; ++t)
          af[t]  = *(const bf16x8*)&As[(kk * 4 + t) * 512 + l * 8];
#pragma unroll
        for (int t = 0; t < 2; ++t)
          bfr[t] = *(const bf16x8*)&Bs[(kk * 8 + w * 2 + t) * 512 + l * 8];
#pragma unroll
        for (int mt = 0; mt < 4; ++mt)
#pragma unroll
          for (int nt = 0; nt < 2; ++nt)
            acc[mt][nt] = __builtin_amdgcn_mfma_f32_16x16x32_bf16(af[mt], bfr[nt], acc[mt][nt], 0, 0, 0);
      }
      __syncthreads();
    }
  }

#pragma unroll
  for (int mt = 0; mt < 4; ++mt)
#pragma unroll
    for (int nt = 0; nt < 2; ++nt)
#pragma unroll
      for (int r = 0; r < 4; ++r) {
        const int row = h * 64 + mt * 16 + lh * 4 + r;
        const int col = d0 + w * 32 + nt * 16 + ll;
        ab[((size_t)b * SEQ + row) * D_MODEL + col] = (bf16)(acc[mt][nt][r] * scale);
      }
}

// ---------------- launcher ----------------
extern "C" void kernel_launch(void* const* d_in, const int* in_sizes, int n_in,
                              void* d_out, int out_size, void* d_ws, size_t ws_size,
                              hipStream_t stream)
{
  (void)in_sizes; (void)n_in; (void)out_size;

  const float* x  = (const float*)d_in[0];
  const float* Wq = (const float*)d_in[1];
  const float* bq = (const float*)d_in[2];
  const float* Wk = (const float*)d_in[3];
  const float* bk = (const float*)d_in[4];
  const float* Wv = (const float*)d_in[5];
  const float* bv = (const float*)d_in[6];
  const float* Wo = (const float*)d_in[7];
  const float* bo = (const float*)d_in[8];

  // workspace layout (bytes): xb 32M | wt 8M | qb 32M | kb 32M | vt 32M | ab 32M = 168 MiB
  // P (8.26 MB) aliases xb: xb's last use is gemm_qkv, P's first write is after.
  if (ws_size < (size_t)176160768) return;
  char* ws = (char*)d_ws;
  bf16* xb = (bf16*)(ws);
  bf16* pb = (bf16*)(ws);                  // P[b][win][128][128] bf16, aliases xb
  bf16* wt = (bf16*)(ws + 33554432);
  bf16* qb = (bf16*)(ws + 41943040);
  bf16* kb = (bf16*)(ws + 75497472);
  bf16* vt = (bf16*)(ws + 109051904);
  bf16* ab = (bf16*)(ws + 142606336);

  cvt_x_kernel<<<16384, 256, 0, stream>>>(x, xb);
  cvt_wt_kernel<<<dim3(32, 32, 4), 256, 0, stream>>>(Wq, Wk, Wv, Wo, wt);

  gemm_qkv<<<3072, 256, 0, stream>>>(xb, wt, bq, bk, bv, qb, kb, vt);

  qk_softmax<<<dim3(126, BATCH), 256, 0, stream>>>(qb, kb, pb);
  pv_gather<<<dim3(8, 64, BATCH), 256, 0, stream>>>(pb, vt, ab);

  gemm_out<<<1024, 256, 0, stream>>>(ab, wt + 3145728, bo, (float*)d_out);
}

// Round 4
// 497.871 us; speedup vs baseline: 1.2215x; 1.0015x over previous
//
#include <hip/hip_runtime.h>
#include <stdint.h>
#include <stddef.h>

#define D_MODEL 1024
#define SEQ     4096
#define BATCH   4
#define MTOT    (BATCH*SEQ)     // 16384
#define NWIN    63

typedef __bf16 bf16;
typedef __bf16 bf16x8 __attribute__((ext_vector_type(8)));
typedef __bf16 bf16x4 __attribute__((ext_vector_type(4)));
typedef float  floatx4 __attribute__((ext_vector_type(4)));

// async global->LDS, 16B per lane. LDS dest is wave-uniform base + lane*16.
__device__ __forceinline__ void async_ld16(const void* g, void* l) {
  __builtin_amdgcn_global_load_lds(
      (const __attribute__((address_space(1))) unsigned int*)g,
      (__attribute__((address_space(3))) unsigned int*)l,
      16, 0, 0);
}

// ---------------- elementwise converts ----------------

__global__ __launch_bounds__(256)
void cvt_x_kernel(const float* __restrict__ x, bf16* __restrict__ xb)
{
  const int i = blockIdx.x * 256 + threadIdx.x;   // exactly 4M threads (16M elems /4)
  const float4 v = ((const float4*)x)[i];
  bf16x4 o = { (bf16)v.x, (bf16)v.y, (bf16)v.z, (bf16)v.w };
  ((bf16x4*)xb)[i] = o;
}

// W (fp32, [K][N]) -> Wt (bf16, [N][K]) for 4 weight matrices (blockIdx.z selects).
// Packed contiguously: rows 0..1023 = Wq^T, 1024..2047 = Wk^T, 2048..3071 = Wv^T,
// 3072..4095 = Wo^T -- so the fused QKV GEMM can use rows 0..3071 directly.
__global__ __launch_bounds__(256)
void cvt_wt_kernel(const float* __restrict__ W0, const float* __restrict__ W1,
                   const float* __restrict__ W2, const float* __restrict__ W3,
                   bf16* __restrict__ wt)
{
  __shared__ float tile[32][33];
  const float* Wsel = (blockIdx.z == 0) ? W0 : (blockIdx.z == 1) ? W1
                    : (blockIdx.z == 2) ? W2 : W3;
  bf16* Wt = wt + (size_t)blockIdx.z * D_MODEL * D_MODEL;
  const int tx = threadIdx.x & 31, ty = threadIdx.x >> 5;  // 32 x 8
  const int tn = blockIdx.x * 32, tk = blockIdx.y * 32;
#pragma unroll
  for (int j = 0; j < 32; j += 8)
    tile[ty + j][tx] = Wsel[(size_t)(tk + ty + j) * D_MODEL + (tn + tx)];
  __syncthreads();
#pragma unroll
  for (int j = 0; j < 32; j += 8)
    Wt[(size_t)(tn + ty + j) * D_MODEL + (tk + tx)] = (bf16)tile[tx][ty + j];
}

// ---------------- shared GEMM core ----------------
// 128x128 tile, BK=64, 4 waves (2x2 of 64x64), mfma_f32_16x16x32_bf16, BT form.
// LDS fragment-major: frag f, 1KB each; lane l owns bytes [16l,16l+16).
__device__ __forceinline__ void gemm_core(const bf16* __restrict__ A,
                                          const bf16* __restrict__ Bt,
                                          int Kdim, int m0, int n0,
                                          bf16* As, bf16* Bs,
                                          floatx4 (&acc)[4][4],
                                          int w, int l)
{
  const int ll = l & 15, lh = l >> 4;
  const int wm = w >> 1, wn = w & 1;

  for (int k0 = 0; k0 < Kdim; k0 += 64) {
#pragma unroll
    for (int i = 0; i < 4; ++i) {
      const int f = w * 4 + i;
      const int mt = f & 7, kk = f >> 3;
      async_ld16(A  + (size_t)(m0 + mt * 16 + ll) * Kdim + (k0 + kk * 32 + lh * 8),
                 &As[f * 512 + l * 8]);
      async_ld16(Bt + (size_t)(n0 + mt * 16 + ll) * Kdim + (k0 + kk * 32 + lh * 8),
                 &Bs[f * 512 + l * 8]);
    }
    __syncthreads();
#pragma unroll
    for (int kk = 0; kk < 2; ++kk) {
      bf16x8 af[4], bfr[4];
#pragma unroll
      for (int t = 0; t < 4; ++t) {
        af[t]  = *(const bf16x8*)&As[(kk * 8 + wm * 4 + t) * 512 + l * 8];
        bfr[t] = *(const bf16x8*)&Bs[(kk * 8 + wn * 4 + t) * 512 + l * 8];
      }
#pragma unroll
      for (int mt = 0; mt < 4; ++mt)
#pragma unroll
        for (int nt = 0; nt < 4; ++nt)
          acc[mt][nt] = __builtin_amdgcn_mfma_f32_16x16x32_bf16(af[mt], bfr[nt], acc[mt][nt], 0, 0, 0);
    }
    __syncthreads();
  }
}

// ---------------- fused QKV projection GEMM ----------------
// C[16384][3072] = xb @ [Wq|Wk|Wv] + [bq|bk|bv]; n<1024 -> qb, <2048 -> kb,
// else -> vt (transposed per batch). Grid 3072 1-D, XCD-swizzled.
// Each XCD owns m-blocks [xcd*16, xcd*16+16), processed as 4 subchunks of
// 4 m-blocks; within a subchunk the full n-sweep runs with m fastest.
// Working set per XCD: 4 A-blocks (1MB) + B-tile (256KB) << 4MB L2, so
// staging loads are L2 hits after first touch (latency ~200 vs ~900 cyc).
__global__ __launch_bounds__(256)
void gemm_qkv(const bf16* __restrict__ A, const bf16* __restrict__ Bt,
              const float* __restrict__ bq, const float* __restrict__ bk,
              const float* __restrict__ bv,
              bf16* __restrict__ qo, bf16* __restrict__ ko, bf16* __restrict__ vto)
{
  __shared__ __attribute__((aligned(16))) bf16 As[8192];  // 16KB
  __shared__ __attribute__((aligned(16))) bf16 Bs[8192];  // 16KB
  const int tid = threadIdx.x;
  const int w = tid >> 6, l = tid & 63;
  const int ll = l & 15, lh = l >> 4;
  const int wm = w >> 1, wn = w & 1;

  const int idx = blockIdx.x;            // 0..3071
  const int xcd = idx & 7;
  const int local = idx >> 3;            // 0..383 = sub*96 + n*4 + msub
  const int msub = local & 3;
  const int nblk = (local >> 2) % 24;
  const int sub  = local / 96;           // 0..3
  const int mblk = xcd * 16 + sub * 4 + msub;
  const int m0 = mblk * 128, n0 = nblk * 128;

  floatx4 acc[4][4];
#pragma unroll
  for (int i = 0; i < 4; ++i)
#pragma unroll
    for (int j = 0; j < 4; ++j) acc[i][j] = (floatx4)0.f;

  gemm_core(A, Bt, D_MODEL, m0, n0, As, Bs, acc, w, l);

  const int sel = n0 >> 10;              // 0=q 1=k 2=v (block-uniform)
  const int ncl = n0 & 1023;             // column base within the 1024-wide output
  const float* bias = (sel == 0) ? bq : (sel == 1) ? bk : bv;

#pragma unroll
  for (int mt = 0; mt < 4; ++mt) {
#pragma unroll
    for (int nt = 0; nt < 4; ++nt) {
      const int colL = ncl + wn * 64 + nt * 16 + ll;
      const float bvv = bias[colL];
#pragma unroll
      for (int r = 0; r < 4; ++r) {
        const int row = m0 + wm * 64 + mt * 16 + lh * 4 + r;
        const float v = acc[mt][nt][r] + bvv;
        if (sel == 0) {
          qo[(size_t)row * D_MODEL + colL] = (bf16)v;
        } else if (sel == 1) {
          ko[(size_t)row * D_MODEL + colL] = (bf16)v;
        } else {
          const int bb = row >> 12, s = row & 4095;
          vto[((size_t)bb * D_MODEL + colL) * SEQ + s] = (bf16)v;
        }
      }
    }
  }
}

// ---------------- output projection GEMM (fp32 out) ----------------
// Same subchunked swizzle; 8 n-blocks.
__global__ __launch_bounds__(256)
void gemm_out(const bf16* __restrict__ A, const bf16* __restrict__ Bt,
              const float* __restrict__ bias, float* __restrict__ C)
{
  __shared__ __attribute__((aligned(16))) bf16 As[8192];
  __shared__ __attribute__((aligned(16))) bf16 Bs[8192];
  const int tid = threadIdx.x;
  const int w = tid >> 6, l = tid & 63;
  const int ll = l & 15, lh = l >> 4;
  const int wm = w >> 1, wn = w & 1;

  const int idx = blockIdx.x;            // 0..1023
  const int xcd = idx & 7;
  const int local = idx >> 3;            // 0..127 = sub*32 + n*4 + msub
  const int msub = local & 3;
  const int nblk = (local >> 2) & 7;
  const int sub  = local >> 5;           // 0..3
  const int mblk = xcd * 16 + sub * 4 + msub;
  const int m0 = mblk * 128, n0 = nblk * 128;

  floatx4 acc[4][4];
#pragma unroll
  for (int i = 0; i < 4; ++i)
#pragma unroll
    for (int j = 0; j < 4; ++j) acc[i][j] = (floatx4)0.f;

  gemm_core(A, Bt, D_MODEL, m0, n0, As, Bs, acc, w, l);

#pragma unroll
  for (int mt = 0; mt < 4; ++mt) {
#pragma unroll
    for (int nt = 0; nt < 4; ++nt) {
      const int col = n0 + wn * 64 + nt * 16 + ll;
      const float bvv = bias[col];
#pragma unroll
      for (int r = 0; r < 4; ++r) {
        const int row = m0 + wm * 64 + mt * 16 + lh * 4 + r;
        C[(size_t)row * D_MODEL + col] = acc[mt][nt][r] + bvv;
      }
    }
  }
}

// ---------------- kernel A: QK^T + softmax -> normalized P (bf16) ----------------
// One block per (q-half, window, batch): 64 q rows x 128 keys, K=1024 contraction.
__global__ __launch_bounds__(256)
void qk_softmax(const bf16* __restrict__ qb, const bf16* __restrict__ kb,
                bf16* __restrict__ Pg)
{
  __shared__ __attribute__((aligned(16))) bf16 As[4096];   // Q 64x64, 8KB
  __shared__ __attribute__((aligned(16))) bf16 Bs[8192];   // K 128x64, 16KB
  __shared__ float redM[4][64];
  __shared__ float redS[4][64];

  const int tid = threadIdx.x;
  const int w = tid >> 6, l = tid & 63, ll = l & 15, lh = l >> 4;
  const int wh = blockIdx.x;                 // 0..125
  const int win = wh >> 1, half = wh & 1;
  const int b = blockIdx.y;

  const bf16* Aq = qb + ((size_t)b * SEQ + win * 64 + half * 64) * D_MODEL;
  const bf16* Ak = kb + ((size_t)b * SEQ + win * 64) * D_MODEL;

  floatx4 acc[4][2];
#pragma unroll
  for (int i = 0; i < 4; ++i)
#pragma unroll
    for (int j = 0; j < 2; ++j) acc[i][j] = (floatx4)0.f;

  for (int c0 = 0; c0 < D_MODEL; c0 += 64) {
#pragma unroll
    for (int i = 0; i < 2; ++i) {            // Q: 8 frags (4 m x 2 kk)
      const int f = w * 2 + i;
      const int mt = f & 3, kk = f >> 2;
      async_ld16(Aq + (size_t)(mt * 16 + ll) * D_MODEL + (c0 + kk * 32 + lh * 8),
                 &As[f * 512 + l * 8]);
    }
#pragma unroll
    for (int i = 0; i < 4; ++i) {            // K: 16 frags (8 n x 2 kk)
      const int f = w * 4 + i;
      const int mt = f & 7, kk = f >> 3;
      async_ld16(Ak + (size_t)(mt * 16 + ll) * D_MODEL + (c0 + kk * 32 + lh * 8),
                 &Bs[f * 512 + l * 8]);
    }
    __syncthreads();
#pragma unroll
    for (int kk = 0; kk < 2; ++kk) {
      bf16x8 af[4], bfr[2];
#pragma unroll
      for (int t = 0; t < 4; ++t)
        af[t]  = *(const bf16x8*)&As[(kk * 4 + t) * 512 + l * 8];
#pragma unroll
      for (int t = 0; t < 2; ++t)
        bfr[t] = *(const bf16x8*)&Bs[(kk * 8 + w * 2 + t) * 512 + l * 8];
#pragma unroll
      for (int mt = 0; mt < 4; ++mt)
#pragma unroll
        for (int nt = 0; nt < 2; ++nt)
          acc[mt][nt] = __builtin_amdgcn_mfma_f32_16x16x32_bf16(af[mt], bfr[nt], acc[mt][nt], 0, 0, 0);
    }
    __syncthreads();
  }

  // scale by 1/sqrt(HEAD_DIM)=0.125
#pragma unroll
  for (int mt = 0; mt < 4; ++mt)
#pragma unroll
    for (int nt = 0; nt < 2; ++nt)
#pragma unroll
      for (int r = 0; r < 4; ++r) acc[mt][nt][r] *= 0.125f;

#pragma unroll
  for (int mt = 0; mt < 4; ++mt)
#pragma unroll
    for (int r = 0; r < 4; ++r) {
      float m = fmaxf(acc[mt][0][r], acc[mt][1][r]);
      m = fmaxf(m, __shfl_xor(m, 1));
      m = fmaxf(m, __shfl_xor(m, 2));
      m = fmaxf(m, __shfl_xor(m, 4));
      m = fmaxf(m, __shfl_xor(m, 8));
      if (ll == 0) redM[w][mt * 16 + lh * 4 + r] = m;
    }
  __syncthreads();

#pragma unroll
  for (int mt = 0; mt < 4; ++mt)
#pragma unroll
    for (int r = 0; r < 4; ++r) {
      const int row = mt * 16 + lh * 4 + r;
      const float m = fmaxf(fmaxf(redM[0][row], redM[1][row]),
                            fmaxf(redM[2][row], redM[3][row]));
      const float e0 = __expf(acc[mt][0][r] - m);
      const float e1 = __expf(acc[mt][1][r] - m);
      acc[mt][0][r] = e0; acc[mt][1][r] = e1;
      float s = e0 + e1;
      s += __shfl_xor(s, 1);
      s += __shfl_xor(s, 2);
      s += __shfl_xor(s, 4);
      s += __shfl_xor(s, 8);
      if (ll == 0) redS[w][row] = s;
    }
  __syncthreads();

  bf16* Pb = Pg + ((size_t)(b * NWIN + win) * 128 + half * 64) * 128;
#pragma unroll
  for (int mt = 0; mt < 4; ++mt)
#pragma unroll
    for (int r = 0; r < 4; ++r) {
      const int row = mt * 16 + lh * 4 + r;
      const float inv = 1.f / (redS[0][row] + redS[1][row] + redS[2][row] + redS[3][row]);
#pragma unroll
      for (int nt = 0; nt < 2; ++nt)
        Pb[(size_t)row * 128 + w * 32 + nt * 16 + ll] = (bf16)(acc[mt][nt][r] * inv);
    }
}

// ---------------- kernel B: gather-form P@V, averaged, direct bf16 store ----------
__global__ __launch_bounds__(256)
void pv_gather(const bf16* __restrict__ Pg, const bf16* __restrict__ vt,
               bf16* __restrict__ ab)
{
  __shared__ __attribute__((aligned(16))) bf16 As[4096];   // P 64x64, 8KB
  __shared__ __attribute__((aligned(16))) bf16 Bs[8192];   // Vt 128x64, 16KB

  const int tid = threadIdx.x;
  const int w = tid >> 6, l = tid & 63, ll = l & 15, lh = l >> 4;
  const int d0 = blockIdx.x * 128;           // 0..7
  const int h  = blockIdx.y;                 // 0..63
  const int b  = blockIdx.z;

  int wseg[2], roff[2];
  int nseg = 0;
  if (h >= 1)        { wseg[nseg] = h - 1; roff[nseg] = 64; ++nseg; }
  if (h <= NWIN - 1) { wseg[nseg] = h;     roff[nseg] = 0;  ++nseg; }
  const float scale = (nseg == 2) ? 0.5f : 1.0f;

  floatx4 acc[4][2];
#pragma unroll
  for (int i = 0; i < 4; ++i)
#pragma unroll
    for (int j = 0; j < 2; ++j) acc[i][j] = (floatx4)0.f;

  for (int sg = 0; sg < nseg; ++sg) {
    const bf16* Pseg = Pg + ((size_t)(b * NWIN + wseg[sg]) * 128 + roff[sg]) * 128;
    const bf16* Vseg = vt + ((size_t)b * D_MODEL + d0) * SEQ + wseg[sg] * 64;
    for (int c0 = 0; c0 < 128; c0 += 64) {
#pragma unroll
      for (int i = 0; i < 2; ++i) {          // P: 8 frags (4 m x 2 kk)
        const int f = w * 2 + i;
        const int mt = f & 3, kk = f >> 2;
        async_ld16(Pseg + (size_t)(mt * 16 + ll) * 128 + (c0 + kk * 32 + lh * 8),
                   &As[f * 512 + l * 8]);
      }
#pragma unroll
      for (int i = 0; i < 4; ++i) {          // Vt: 16 frags (8 n x 2 kk)
        const int f = w * 4 + i;
        const int mt = f & 7, kk = f >> 3;
        async_ld16(Vseg + (size_t)(mt * 16 + ll) * SEQ + (c0 + kk * 32 + lh * 8),
                   &Bs[f * 512 + l * 8]);
      }
      __syncthreads();
#pragma unroll
      for (int kk = 0; kk < 2; ++kk) {
        bf16x8 af[4], bfr[2];
#pragma unroll
        for (int t = 0; t < 4; ++t)
          af[t]  = *(const bf16x8*)&As[(kk * 4 + t) * 512 + l * 8];
#pragma unroll
        for (int t = 0; t < 2; ++t)
          bfr[t] = *(const bf16x8*)&Bs[(kk * 8 + w * 2 + t) * 512 + l * 8];
#pragma unroll
        for (int mt = 0; mt < 4; ++mt)
#pragma unroll
          for (int nt = 0; nt < 2; ++nt)
            acc[mt][nt] = __builtin_amdgcn_mfma_f32_16x16x32_bf16(af[mt], bfr[nt], acc[mt][nt], 0, 0, 0);
      }
      __syncthreads();
    }
  }

#pragma unroll
  for (int mt = 0; mt < 4; ++mt)
#pragma unroll
    for (int nt = 0; nt < 2; ++nt)
#pragma unroll
      for (int r = 0; r < 4; ++r) {
        const int row = h * 64 + mt * 16 + lh * 4 + r;
        const int col = d0 + w * 32 + nt * 16 + ll;
        ab[((size_t)b * SEQ + row) * D_MODEL + col] = (bf16)(acc[mt][nt][r] * scale);
      }
}

// ---------------- launcher ----------------
extern "C" void kernel_launch(void* const* d_in, const int* in_sizes, int n_in,
                              void* d_out, int out_size, void* d_ws, size_t ws_size,
                              hipStream_t stream)
{
  (void)in_sizes; (void)n_in; (void)out_size;

  const float* x  = (const float*)d_in[0];
  const float* Wq = (const float*)d_in[1];
  const float* bq = (const float*)d_in[2];
  const float* Wk = (const float*)d_in[3];
  const float* bk = (const float*)d_in[4];
  const float* Wv = (const float*)d_in[5];
  const float* bv = (const float*)d_in[6];
  const float* Wo = (const float*)d_in[7];
  const float* bo = (const float*)d_in[8];

  // workspace layout (bytes): xb 32M | wt 8M | qb 32M | kb 32M | vt 32M | ab 32M = 168 MiB
  // P (8.26 MB) aliases xb: xb's last use is gemm_qkv, P's first write is after.
  if (ws_size < (size_t)176160768) return;
  char* ws = (char*)d_ws;
  bf16* xb = (bf16*)(ws);
  bf16* pb = (bf16*)(ws);                  // P[b][win][128][128] bf16, aliases xb
  bf16* wt = (bf16*)(ws + 33554432);
  bf16* qb = (bf16*)(ws + 41943040);
  bf16* kb = (bf16*)(ws + 75497472);
  bf16* vt = (bf16*)(ws + 109051904);
  bf16* ab = (bf16*)(ws + 142606336);

  cvt_x_kernel<<<16384, 256, 0, stream>>>(x, xb);
  cvt_wt_kernel<<<dim3(32, 32, 4), 256, 0, stream>>>(Wq, Wk, Wv, Wo, wt);

  gemm_qkv<<<3072, 256, 0, stream>>>(xb, wt, bq, bk, bv, qb, kb, vt);

  qk_softmax<<<dim3(126, BATCH), 256, 0, stream>>>(qb, kb, pb);
  pv_gather<<<dim3(8, 64, BATCH), 256, 0, stream>>>(pb, vt, ab);

  gemm_out<<<1024, 256, 0, stream>>>(ab, wt + 3145728, bo, (float*)d_out);
}

// Round 5
// 495.979 us; speedup vs baseline: 1.2262x; 1.0038x over previous
//
#include <hip/hip_runtime.h>
#include <stdint.h>
#include <stddef.h>

#define D_MODEL 1024
#define SEQ     4096
#define BATCH   4
#define MTOT    (BATCH*SEQ)     // 16384
#define NWIN    63

typedef __bf16 bf16;
typedef __bf16 bf16x8 __attribute__((ext_vector_type(8)));
typedef __bf16 bf16x4 __attribute__((ext_vector_type(4)));
typedef float  floatx4 __attribute__((ext_vector_type(4)));

// async global->LDS, 16B per lane (used only by pv_gather now).
__device__ __forceinline__ void async_ld16(const void* g, void* l) {
  __builtin_amdgcn_global_load_lds(
      (const __attribute__((address_space(1))) unsigned int*)g,
      (__attribute__((address_space(3))) unsigned int*)l,
      16, 0, 0);
}

// ---------------- elementwise converts ----------------

__global__ __launch_bounds__(256)
void cvt_x_kernel(const float* __restrict__ x, bf16* __restrict__ xb)
{
  const int i = blockIdx.x * 256 + threadIdx.x;   // exactly 4M threads (16M elems /4)
  const float4 v = ((const float4*)x)[i];
  bf16x4 o = { (bf16)v.x, (bf16)v.y, (bf16)v.z, (bf16)v.w };
  ((bf16x4*)xb)[i] = o;
}

// W (fp32, [K][N]) -> Wt (bf16, [N][K]), packed: rows 0..1023=Wq^T, ..., 3072..4095=Wo^T
__global__ __launch_bounds__(256)
void cvt_wt_kernel(const float* __restrict__ W0, const float* __restrict__ W1,
                   const float* __restrict__ W2, const float* __restrict__ W3,
                   bf16* __restrict__ wt)
{
  __shared__ float tile[32][33];
  const float* Wsel = (blockIdx.z == 0) ? W0 : (blockIdx.z == 1) ? W1
                    : (blockIdx.z == 2) ? W2 : W3;
  bf16* Wt = wt + (size_t)blockIdx.z * D_MODEL * D_MODEL;
  const int tx = threadIdx.x & 31, ty = threadIdx.x >> 5;  // 32 x 8
  const int tn = blockIdx.x * 32, tk = blockIdx.y * 32;
#pragma unroll
  for (int j = 0; j < 32; j += 8)
    tile[ty + j][tx] = Wsel[(size_t)(tk + ty + j) * D_MODEL + (tn + tx)];
  __syncthreads();
#pragma unroll
  for (int j = 0; j < 32; j += 8)
    Wt[(size_t)(tn + ty + j) * D_MODEL + (tk + tx)] = (bf16)tile[tx][ty + j];
}

// ---------------- pipelined GEMM core ----------------
// 128x128 tile, BK=64, 4 waves (2x2 of 64x64), mfma_f32_16x16x32_bf16, BT form.
// Register-staged single-barrier double-buffered pipeline:
//   loads for t+1 issued before compute of t; vmcnt wait lands at ds_write
//   (after the MFMA block); ONE barrier per K-iteration.
// LDS: As/Bs are 2x8192 bf16 double buffers (64KB total).
__device__ __forceinline__ void gemm_core_pipe(const bf16* __restrict__ A,
                                               const bf16* __restrict__ Bt,
                                               int Kdim, int m0, int n0,
                                               bf16* As, bf16* Bs,
                                               floatx4 (&acc)[4][4],
                                               int w, int l)
{
  const int ll = l & 15, lh = l >> 4;
  const int wm = w >> 1, wn = w & 1;

  bf16x8 ar[4], br[4];   // staging regs: 8 frags x 16B = 32 VGPRs

  auto load_regs = [&](int k0) {
#pragma unroll
    for (int i = 0; i < 4; ++i) {
      const int f = w * 4 + i;
      const int mt = f & 7, kk = f >> 3;
      ar[i] = *(const bf16x8*)(A  + (size_t)(m0 + mt * 16 + ll) * Kdim + (k0 + kk * 32 + lh * 8));
      br[i] = *(const bf16x8*)(Bt + (size_t)(n0 + mt * 16 + ll) * Kdim + (k0 + kk * 32 + lh * 8));
    }
  };
  auto store_lds = [&](int buf) {
    bf16* Ad = As + buf * 8192;
    bf16* Bd = Bs + buf * 8192;
#pragma unroll
    for (int i = 0; i < 4; ++i) {
      const int f = w * 4 + i;
      *(bf16x8*)&Ad[f * 512 + l * 8] = ar[i];
      *(bf16x8*)&Bd[f * 512 + l * 8] = br[i];
    }
  };

  load_regs(0);
  store_lds(0);
  __syncthreads();

  const int T = Kdim >> 6;
  for (int t = 0; t < T; ++t) {
    if (t + 1 < T) load_regs((t + 1) << 6);      // async, in flight during MFMAs
    const bf16* Ac = As + (t & 1) * 8192;
    const bf16* Bc = Bs + (t & 1) * 8192;
#pragma unroll
    for (int kk = 0; kk < 2; ++kk) {
      bf16x8 af[4], bfr[4];
#pragma unroll
      for (int tt = 0; tt < 4; ++tt) {
        af[tt]  = *(const bf16x8*)&Ac[(kk * 8 + wm * 4 + tt) * 512 + l * 8];
        bfr[tt] = *(const bf16x8*)&Bc[(kk * 8 + wn * 4 + tt) * 512 + l * 8];
      }
#pragma unroll
      for (int mt = 0; mt < 4; ++mt)
#pragma unroll
        for (int nt = 0; nt < 4; ++nt)
          acc[mt][nt] = __builtin_amdgcn_mfma_f32_16x16x32_bf16(af[mt], bfr[nt], acc[mt][nt], 0, 0, 0);
    }
    if (t + 1 < T) store_lds((t + 1) & 1);       // vmcnt wait happens here
    __syncthreads();                              // one barrier per iteration
  }
}

// ---------------- fused QKV projection GEMM ----------------
__global__ __launch_bounds__(256)
void gemm_qkv(const bf16* __restrict__ A, const bf16* __restrict__ Bt,
              const float* __restrict__ bq, const float* __restrict__ bk,
              const float* __restrict__ bv,
              bf16* __restrict__ qo, bf16* __restrict__ ko, bf16* __restrict__ vto)
{
  __shared__ __attribute__((aligned(16))) bf16 As[16384];  // 2x16KB double buffer
  __shared__ __attribute__((aligned(16))) bf16 Bs[16384];
  const int tid = threadIdx.x;
  const int w = tid >> 6, l = tid & 63;
  const int ll = l & 15, lh = l >> 4;
  const int wm = w >> 1, wn = w & 1;

  const int idx = blockIdx.x;            // 0..3071
  const int xcd = idx & 7;
  const int local = idx >> 3;            // 0..383 = sub*96 + n*4 + msub
  const int msub = local & 3;
  const int nblk = (local >> 2) % 24;
  const int sub  = local / 96;           // 0..3
  const int mblk = xcd * 16 + sub * 4 + msub;
  const int m0 = mblk * 128, n0 = nblk * 128;

  floatx4 acc[4][4];
#pragma unroll
  for (int i = 0; i < 4; ++i)
#pragma unroll
    for (int j = 0; j < 4; ++j) acc[i][j] = (floatx4)0.f;

  gemm_core_pipe(A, Bt, D_MODEL, m0, n0, As, Bs, acc, w, l);

  const int sel = n0 >> 10;              // 0=q 1=k 2=v (block-uniform)
  const int ncl = n0 & 1023;
  const float* bias = (sel == 0) ? bq : (sel == 1) ? bk : bv;

#pragma unroll
  for (int mt = 0; mt < 4; ++mt) {
#pragma unroll
    for (int nt = 0; nt < 4; ++nt) {
      const int colL = ncl + wn * 64 + nt * 16 + ll;
      const float bvv = bias[colL];
#pragma unroll
      for (int r = 0; r < 4; ++r) {
        const int row = m0 + wm * 64 + mt * 16 + lh * 4 + r;
        const float v = acc[mt][nt][r] + bvv;
        if (sel == 0) {
          qo[(size_t)row * D_MODEL + colL] = (bf16)v;
        } else if (sel == 1) {
          ko[(size_t)row * D_MODEL + colL] = (bf16)v;
        } else {
          const int bb = row >> 12, s = row & 4095;
          vto[((size_t)bb * D_MODEL + colL) * SEQ + s] = (bf16)v;
        }
      }
    }
  }
}

// ---------------- output projection GEMM (fp32 out) ----------------
__global__ __launch_bounds__(256)
void gemm_out(const bf16* __restrict__ A, const bf16* __restrict__ Bt,
              const float* __restrict__ bias, float* __restrict__ C)
{
  __shared__ __attribute__((aligned(16))) bf16 As[16384];
  __shared__ __attribute__((aligned(16))) bf16 Bs[16384];
  const int tid = threadIdx.x;
  const int w = tid >> 6, l = tid & 63;
  const int ll = l & 15, lh = l >> 4;
  const int wm = w >> 1, wn = w & 1;

  const int idx = blockIdx.x;            // 0..1023
  const int xcd = idx & 7;
  const int local = idx >> 3;            // 0..127 = sub*32 + n*4 + msub
  const int msub = local & 3;
  const int nblk = (local >> 2) & 7;
  const int sub  = local >> 5;           // 0..3
  const int mblk = xcd * 16 + sub * 4 + msub;
  const int m0 = mblk * 128, n0 = nblk * 128;

  floatx4 acc[4][4];
#pragma unroll
  for (int i = 0; i < 4; ++i)
#pragma unroll
    for (int j = 0; j < 4; ++j) acc[i][j] = (floatx4)0.f;

  gemm_core_pipe(A, Bt, D_MODEL, m0, n0, As, Bs, acc, w, l);

#pragma unroll
  for (int mt = 0; mt < 4; ++mt) {
#pragma unroll
    for (int nt = 0; nt < 4; ++nt) {
      const int col = n0 + wn * 64 + nt * 16 + ll;
      const float bvv = bias[col];
#pragma unroll
      for (int r = 0; r < 4; ++r) {
        const int row = m0 + wm * 64 + mt * 16 + lh * 4 + r;
        C[(size_t)row * D_MODEL + col] = acc[mt][nt][r] + bvv;
      }
    }
  }
}

// ---------------- kernel A: QK^T + softmax -> normalized P (bf16) ----------------
// One block per (q-half, window, batch): 64 q rows x 128 keys, K=1024 contraction.
// Same register-staged single-barrier pipeline (Q: 2 frags/wave, K: 4 frags/wave).
__global__ __launch_bounds__(256)
void qk_softmax(const bf16* __restrict__ qb, const bf16* __restrict__ kb,
                bf16* __restrict__ Pg)
{
  __shared__ __attribute__((aligned(16))) bf16 As[8192];   // Q 2x(64x64), 16KB
  __shared__ __attribute__((aligned(16))) bf16 Bs[16384];  // K 2x(128x64), 32KB
  __shared__ float redM[4][64];
  __shared__ float redS[4][64];

  const int tid = threadIdx.x;
  const int w = tid >> 6, l = tid & 63, ll = l & 15, lh = l >> 4;
  const int wh = blockIdx.x;                 // 0..125
  const int win = wh >> 1, half = wh & 1;
  const int b = blockIdx.y;

  const bf16* Aq = qb + ((size_t)b * SEQ + win * 64 + half * 64) * D_MODEL;
  const bf16* Ak = kb + ((size_t)b * SEQ + win * 64) * D_MODEL;

  floatx4 acc[4][2];
#pragma unroll
  for (int i = 0; i < 4; ++i)
#pragma unroll
    for (int j = 0; j < 2; ++j) acc[i][j] = (floatx4)0.f;

  bf16x8 qr[2], kr[4];

  auto load_regs = [&](int c0) {
#pragma unroll
    for (int i = 0; i < 2; ++i) {            // Q: 8 frags (4 m x 2 kk)
      const int f = w * 2 + i;
      const int mt = f & 3, kk = f >> 2;
      qr[i] = *(const bf16x8*)(Aq + (size_t)(mt * 16 + ll) * D_MODEL + (c0 + kk * 32 + lh * 8));
    }
#pragma unroll
    for (int i = 0; i < 4; ++i) {            // K: 16 frags (8 n x 2 kk)
      const int f = w * 4 + i;
      const int mt = f & 7, kk = f >> 3;
      kr[i] = *(const bf16x8*)(Ak + (size_t)(mt * 16 + ll) * D_MODEL + (c0 + kk * 32 + lh * 8));
    }
  };
  auto store_lds = [&](int buf) {
    bf16* Ad = As + buf * 4096;
    bf16* Bd = Bs + buf * 8192;
#pragma unroll
    for (int i = 0; i < 2; ++i) {
      const int f = w * 2 + i;
      *(bf16x8*)&Ad[f * 512 + l * 8] = qr[i];
    }
#pragma unroll
    for (int i = 0; i < 4; ++i) {
      const int f = w * 4 + i;
      *(bf16x8*)&Bd[f * 512 + l * 8] = kr[i];
    }
  };

  load_regs(0);
  store_lds(0);
  __syncthreads();

  for (int t = 0; t < 16; ++t) {
    if (t + 1 < 16) load_regs((t + 1) << 6);
    const bf16* Ac = As + (t & 1) * 4096;
    const bf16* Bc = Bs + (t & 1) * 8192;
#pragma unroll
    for (int kk = 0; kk < 2; ++kk) {
      bf16x8 af[4], bfr[2];
#pragma unroll
      for (int tt = 0; tt < 4; ++tt)
        af[tt]  = *(const bf16x8*)&Ac[(kk * 4 + tt) * 512 + l * 8];
#pragma unroll
      for (int tt = 0; tt < 2; ++tt)
        bfr[tt] = *(const bf16x8*)&Bc[(kk * 8 + w * 2 + tt) * 512 + l * 8];
#pragma unroll
      for (int mt = 0; mt < 4; ++mt)
#pragma unroll
        for (int nt = 0; nt < 2; ++nt)
          acc[mt][nt] = __builtin_amdgcn_mfma_f32_16x16x32_bf16(af[mt], bfr[nt], acc[mt][nt], 0, 0, 0);
    }
    if (t + 1 < 16) store_lds((t + 1) & 1);
    __syncthreads();
  }

  // scale by 1/sqrt(HEAD_DIM)=0.125
#pragma unroll
  for (int mt = 0; mt < 4; ++mt)
#pragma unroll
    for (int nt = 0; nt < 2; ++nt)
#pragma unroll
      for (int r = 0; r < 4; ++r) acc[mt][nt][r] *= 0.125f;

#pragma unroll
  for (int mt = 0; mt < 4; ++mt)
#pragma unroll
    for (int r = 0; r < 4; ++r) {
      float m = fmaxf(acc[mt][0][r], acc[mt][1][r]);
      m = fmaxf(m, __shfl_xor(m, 1));
      m = fmaxf(m, __shfl_xor(m, 2));
      m = fmaxf(m, __shfl_xor(m, 4));
      m = fmaxf(m, __shfl_xor(m, 8));
      if (ll == 0) redM[w][mt * 16 + lh * 4 + r] = m;
    }
  __syncthreads();

#pragma unroll
  for (int mt = 0; mt < 4; ++mt)
#pragma unroll
    for (int r = 0; r < 4; ++r) {
      const int row = mt * 16 + lh * 4 + r;
      const float m = fmaxf(fmaxf(redM[0][row], redM[1][row]),
                            fmaxf(redM[2][row], redM[3][row]));
      const float e0 = __expf(acc[mt][0][r] - m);
      const float e1 = __expf(acc[mt][1][r] - m);
      acc[mt][0][r] = e0; acc[mt][1][r] = e1;
      float s = e0 + e1;
      s += __shfl_xor(s, 1);
      s += __shfl_xor(s, 2);
      s += __shfl_xor(s, 4);
      s += __shfl_xor(s, 8);
      if (ll == 0) redS[w][row] = s;
    }
  __syncthreads();

  bf16* Pb = Pg + ((size_t)(b * NWIN + win) * 128 + half * 64) * 128;
#pragma unroll
  for (int mt = 0; mt < 4; ++mt)
#pragma unroll
    for (int r = 0; r < 4; ++r) {
      const int row = mt * 16 + lh * 4 + r;
      const float inv = 1.f / (redS[0][row] + redS[1][row] + redS[2][row] + redS[3][row]);
#pragma unroll
      for (int nt = 0; nt < 2; ++nt)
        Pb[(size_t)row * 128 + w * 32 + nt * 16 + ll] = (bf16)(acc[mt][nt][r] * inv);
    }
}

// ---------------- kernel B: gather-form P@V, averaged, direct bf16 store ----------
__global__ __launch_bounds__(256)
void pv_gather(const bf16* __restrict__ Pg, const bf16* __restrict__ vt,
               bf16* __restrict__ ab)
{
  __shared__ __attribute__((aligned(16))) bf16 As[4096];   // P 64x64, 8KB
  __shared__ __attribute__((aligned(16))) bf16 Bs[8192];   // Vt 128x64, 16KB

  const int tid = threadIdx.x;
  const int w = tid >> 6, l = tid & 63, ll = l & 15, lh = l >> 4;
  const int d0 = blockIdx.x * 128;           // 0..7
  const int h  = blockIdx.y;                 // 0..63
  const int b  = blockIdx.z;

  int wseg[2], roff[2];
  int nseg = 0;
  if (h >= 1)        { wseg[nseg] = h - 1; roff[nseg] = 64; ++nseg; }
  if (h <= NWIN - 1) { wseg[nseg] = h;     roff[nseg] = 0;  ++nseg; }
  const float scale = (nseg == 2) ? 0.5f : 1.0f;

  floatx4 acc[4][2];
#pragma unroll
  for (int i = 0; i < 4; ++i)
#pragma unroll
    for (int j = 0; j < 2; ++j) acc[i][j] = (floatx4)0.f;

  for (int sg = 0; sg < nseg; ++sg) {
    const bf16* Pseg = Pg + ((size_t)(b * NWIN + wseg[sg]) * 128 + roff[sg]) * 128;
    const bf16* Vseg = vt + ((size_t)b * D_MODEL + d0) * SEQ + wseg[sg] * 64;
    for (int c0 = 0; c0 < 128; c0 += 64) {
#pragma unroll
      for (int i = 0; i < 2; ++i) {          // P: 8 frags (4 m x 2 kk)
        const int f = w * 2 + i;
        const int mt = f & 3, kk = f >> 2;
        async_ld16(Pseg + (size_t)(mt * 16 + ll) * 128 + (c0 + kk * 32 + lh * 8),
                   &As[f * 512 + l * 8]);
      }
#pragma unroll
      for (int i = 0; i < 4; ++i) {          // Vt: 16 frags (8 n x 2 kk)
        const int f = w * 4 + i;
        const int mt = f & 7, kk = f >> 3;
        async_ld16(Vseg + (size_t)(mt * 16 + ll) * SEQ + (c0 + kk * 32 + lh * 8),
                   &Bs[f * 512 + l * 8]);
      }
      __syncthreads();
#pragma unroll
      for (int kk = 0; kk < 2; ++kk) {
        bf16x8 af[4], bfr[2];
#pragma unroll
        for (int t = 0; t < 4; ++t)
          af[t]  = *(const bf16x8*)&As[(kk * 4 + t) * 512 + l * 8];
#pragma unroll
        for (int t = 0; t < 2; ++t)
          bfr[t] = *(const bf16x8*)&Bs[(kk * 8 + w * 2 + t) * 512 + l * 8];
#pragma unroll
        for (int mt = 0; mt < 4; ++mt)
#pragma unroll
          for (int nt = 0; nt < 2; ++nt)
            acc[mt][nt] = __builtin_amdgcn_mfma_f32_16x16x32_bf16(af[mt], bfr[nt], acc[mt][nt], 0, 0, 0);
      }
      __syncthreads();
    }
  }

#pragma unroll
  for (int mt = 0; mt < 4; ++mt)
#pragma unroll
    for (int nt = 0; nt < 2; ++nt)
#pragma unroll
      for (int r = 0; r < 4; ++r) {
        const int row = h * 64 + mt * 16 + lh * 4 + r;
        const int col = d0 + w * 32 + nt * 16 + ll;
        ab[((size_t)b * SEQ + row) * D_MODEL + col] = (bf16)(acc[mt][nt][r] * scale);
      }
}

// ---------------- launcher ----------------
extern "C" void kernel_launch(void* const* d_in, const int* in_sizes, int n_in,
                              void* d_out, int out_size, void* d_ws, size_t ws_size,
                              hipStream_t stream)
{
  (void)in_sizes; (void)n_in; (void)out_size;

  const float* x  = (const float*)d_in[0];
  const float* Wq = (const float*)d_in[1];
  const float* bq = (const float*)d_in[2];
  const float* Wk = (const float*)d_in[3];
  const float* bk = (const float*)d_in[4];
  const float* Wv = (const float*)d_in[5];
  const float* bv = (const float*)d_in[6];
  const float* Wo = (const float*)d_in[7];
  const float* bo = (const float*)d_in[8];

  // workspace layout (bytes): xb 32M | wt 8M | qb 32M | kb 32M | vt 32M | ab 32M = 168 MiB
  // P (8.26 MB) aliases xb: xb's last use is gemm_qkv, P's first write is after.
  if (ws_size < (size_t)176160768) return;
  char* ws = (char*)d_ws;
  bf16* xb = (bf16*)(ws);
  bf16* pb = (bf16*)(ws);                  // P[b][win][128][128] bf16, aliases xb
  bf16* wt = (bf16*)(ws + 33554432);
  bf16* qb = (bf16*)(ws + 41943040);
  bf16* kb = (bf16*)(ws + 75497472);
  bf16* vt = (bf16*)(ws + 109051904);
  bf16* ab = (bf16*)(ws + 142606336);

  cvt_x_kernel<<<16384, 256, 0, stream>>>(x, xb);
  cvt_wt_kernel<<<dim3(32, 32, 4), 256, 0, stream>>>(Wq, Wk, Wv, Wo, wt);

  gemm_qkv<<<3072, 256, 0, stream>>>(xb, wt, bq, bk, bv, qb, kb, vt);

  qk_softmax<<<dim3(126, BATCH), 256, 0, stream>>>(qb, kb, pb);
  pv_gather<<<dim3(8, 64, BATCH), 256, 0, stream>>>(pb, vt, ab);

  gemm_out<<<1024, 256, 0, stream>>>(ab, wt + 3145728, bo, (float*)d_out);
}